// Round 1
// 219.001 us; speedup vs baseline: 1.0286x; 1.0286x over previous
//
#include <hip/hip_runtime.h>
#include <hip/hip_bf16.h>
#include <stdint.h>

typedef __bf16 bf16x8 __attribute__((ext_vector_type(8)));
typedef float f32x4 __attribute__((ext_vector_type(4)));

#define ROUTE_BIAS_F 10.0f
#define VOCAB_SZ 32000

// ---------- helpers ----------
__device__ __forceinline__ unsigned short f2bf(float f) {
    union { float f; unsigned u; } v; v.f = f;
    unsigned u = v.u;
    unsigned r = u + 0x7FFFu + ((u >> 16) & 1u);   // RNE
    return (unsigned short)(r >> 16);
}
__device__ __forceinline__ float bf2f(unsigned short s) {
    union { unsigned u; float f; } v; v.u = ((unsigned)s) << 16;
    return v.f;
}
// async 16B global->LDS copy (lds dest wave-uniform; HW adds lane*16)
__device__ __forceinline__ void ld16(const unsigned short* g, unsigned short* l) {
    __builtin_amdgcn_global_load_lds(
        (const __attribute__((address_space(1))) void*)g,
        (__attribute__((address_space(3))) void*)l, 16, 0, 0);
}

// ---------- fused: hidden fp32->bf16 convert + router logits/argmax ----------
// one wave per token: convert 1024 floats AND compute 8 logits.
__global__ void k_prep(const float* __restrict__ hidden, const float* __restrict__ mu,
                       const int* __restrict__ tok_ids, const float* __restrict__ rw,
                       unsigned short* __restrict__ xb, int* __restrict__ eids,
                       int H, int N) {
    int lane = threadIdx.x & 63;
    int wv   = threadIdx.x >> 6;
    int tok  = blockIdx.x * 4 + wv;
    if (tok >= N) return;
    const float4* hp = (const float4*)(hidden + (size_t)tok * H);
    const float4* mp = (const float4*)(mu + (size_t)tok * H);
    const float4* rp = (const float4*)rw;            // [8][H/4]
    ushort4* xp = (ushort4*)(xb + (size_t)tok * H);
    int H4 = H >> 2;                                 // 256
    float acc[8];
#pragma unroll
    for (int e = 0; e < 8; ++e) acc[e] = 0.f;
#pragma unroll
    for (int j = 0; j < 4; ++j) {                    // H4/64 = 4
        int idx = lane + 64 * j;
        float4 h4 = hp[idx];
        ushort4 o;
        o.x = f2bf(h4.x); o.y = f2bf(h4.y); o.z = f2bf(h4.z); o.w = f2bf(h4.w);
        xp[idx] = o;
        float4 m4 = mp[idx];
#pragma unroll
        for (int e = 0; e < 8; ++e) {
            float4 w4 = rp[e * H4 + idx];
            acc[e] += m4.x * w4.x + m4.y * w4.y + m4.z * w4.z + m4.w * w4.w;
        }
    }
#pragma unroll
    for (int e = 0; e < 8; ++e) {
        float v = acc[e];
#pragma unroll
        for (int off = 32; off > 0; off >>= 1) v += __shfl_xor(v, off);
        acc[e] = v;
    }
    if (lane == 0) {
        int t = tok_ids[tok];
        if (t < 0) t = 0;
        if (t > VOCAB_SZ - 1) t = VOCAB_SZ - 1;
        int be = t % 8;
        float best = -1e30f; int bi = 0;
#pragma unroll
        for (int e = 0; e < 8; ++e) {
            float v = acc[e] + (e == be ? ROUTE_BIAS_F : 0.f);
            if (v > best) { best = v; bi = e; }
        }
        eids[tok] = bi;
    }
}

// ---------- merged per-expert transpose+convert for BOTH weights ----------
// z 0..7: gup expert z (R=H, C=F2); z 8..15: dnp expert z-8 (R=Ie, C=H).
// 64x64 tiles, float4 reads, ushort4 writes.
__global__ __launch_bounds__(256) void k_transpose_all(
        const float* __restrict__ gup, const float* __restrict__ dnp,
        unsigned short* __restrict__ wgut, unsigned short* __restrict__ wdnt,
        int H, int F2, int Ie) {
    __shared__ float tile[64][65];
    int z = blockIdx.z;
    const float* inp; unsigned short* outp; int R, C;
    if (z < 8) { R = H; C = F2; inp = gup + (size_t)z * R * C;       outp = wgut + (size_t)z * R * C; }
    else       { R = Ie; C = H; inp = dnp + (size_t)(z - 8) * R * C; outp = wdnt + (size_t)(z - 8) * R * C; }
    int c0 = blockIdx.x * 64, r0 = blockIdx.y * 64;
    if (r0 >= R) return;
    int tid = threadIdx.x;
    int tr = tid >> 4;          // 0..15
    int tc = (tid & 15) * 4;    // 0..60 (step 4)
#pragma unroll
    for (int p = 0; p < 4; ++p) {
        float4 v = *(const float4*)&inp[(size_t)(r0 + tr + 16 * p) * C + c0 + tc];
        tile[tr + 16 * p][tc + 0] = v.x;
        tile[tr + 16 * p][tc + 1] = v.y;
        tile[tr + 16 * p][tc + 2] = v.z;
        tile[tr + 16 * p][tc + 3] = v.w;
    }
    __syncthreads();
#pragma unroll
    for (int p = 0; p < 4; ++p) {
        int c = tr + 16 * p;
        ushort4 o;
        o.x = f2bf(tile[tc + 0][c]);
        o.y = f2bf(tile[tc + 1][c]);
        o.z = f2bf(tile[tc + 2][c]);
        o.w = f2bf(tile[tc + 3][c]);
        *(ushort4*)&outp[(size_t)(c0 + c) * R + r0 + tc] = o;
    }
}

// ---------- router phase B: parallel counting sort ----------
__global__ void k_count(const int* __restrict__ eids,
                        int* __restrict__ blockcnt, int N) {
    __shared__ int cnt[8];
    int tid = threadIdx.x;
    if (tid < 8) cnt[tid] = 0;
    __syncthreads();
    int tok = blockIdx.x * 256 + tid;
    int lane = tid & 63;
    int eid = (tok < N) ? eids[tok] : -1;
#pragma unroll
    for (int e = 0; e < 8; ++e) {
        unsigned long long m = __ballot(eid == e);
        if (lane == 0 && m) atomicAdd(&cnt[e], __popcll(m));
    }
    __syncthreads();
    if (tid < 8) blockcnt[blockIdx.x * 8 + tid] = cnt[tid];
}

__global__ void k_scan(const int* __restrict__ blockcnt,
                       int* __restrict__ counts, int* __restrict__ base_,
                       int* __restrict__ offs, int NB) {   // NB == 32
    __shared__ int tot[8];
    int lane = threadIdx.x;
    int e = lane >> 3, g = lane & 7;
    int v[4];
    int s = 0;
#pragma unroll
    for (int i = 0; i < 4; ++i) { v[i] = s; s += blockcnt[(g * 4 + i) * 8 + e]; }
    int inc = s;
#pragma unroll
    for (int d = 1; d < 8; d <<= 1) {
        int t = __shfl_up(inc, d);
        if (g >= d) inc += t;
    }
    int excl = inc - s;
#pragma unroll
    for (int i = 0; i < 4; ++i) offs[(g * 4 + i) * 8 + e] = excl + v[i];
    if (g == 7) { counts[e] = inc; tot[e] = inc; }
    __syncthreads();
    if (lane == 0) {
        int s2 = 0;
#pragma unroll
        for (int i = 0; i < 8; ++i) { base_[i] = s2; s2 += tot[i]; }
    }
}

__global__ void k_scatter(const int* __restrict__ eids,
                          const int* __restrict__ offs,
                          int* __restrict__ list, int N) {
    __shared__ int wavecnt[4][8];
    int tid = threadIdx.x;
    int lane = tid & 63, wv = tid >> 6;
    int tok = blockIdx.x * 256 + tid;
    int eid = (tok < N) ? eids[tok] : -1;
    unsigned long long below = (1ull << lane) - 1ull;
    int myrank = 0;
#pragma unroll
    for (int e = 0; e < 8; ++e) {
        unsigned long long m = __ballot(eid == e);
        if (lane == 0) wavecnt[wv][e] = __popcll(m);
        if (eid == e) myrank = __popcll(m & below);
    }
    __syncthreads();
    if (eid >= 0) {
        int pre = 0;
        for (int w = 0; w < wv; ++w) pre += wavecnt[w][eid];
        int pos = offs[blockIdx.x * 8 + eid] + pre + myrank;
        list[eid * N + pos] = tok;
    }
}

// ---------- GEMM tile constants ----------
#define TM 128
#define TN 128
#define TK 64
// 256-thread blocks, 4 waves in 2x2, each wave owns a 64x64 output tile
// (m97-class structure: 32KB LDS staged per K-step for 2.1 MFLOP).
// XOR chunk swizzle on global side keeps frag ds_read_b128 at <=2-way aliasing.

// GEMM1 fused: IT[compact_row][Ie] = silu(gate)*up of gather(X) @ Wgu^T.
// B-tile rows interleave gate/up: tile row 2c = gate col (nt*64+c), 2c+1 = up.
__global__ __launch_bounds__(256, 3) void k_gemm_gateup(
    const unsigned short* __restrict__ X,    // [N][H] bf16
    const unsigned short* __restrict__ Wt,   // [E][F2][H] bf16 (f-major)
    unsigned short* __restrict__ IT,         // [N][Ie] bf16 compact rows
    const int* __restrict__ counts, const int* __restrict__ base_,
    const int* __restrict__ list, int N, int H, int Ie) {
    int bid = blockIdx.x;
    int e = bid & 7;                 // XCD-pinned expert
    int t = bid >> 3;
    int nt = t & 7;                  // 8 n-tiles of 64 out cols (128 interleaved)
    int mt = t >> 3;
    int cnt = counts[e];
    int m0 = mt * TM;
    if (m0 >= cnt) return;
    int F2 = 2 * Ie;

    __shared__ __align__(16) unsigned short As[TM * TK];   // 16 KB
    __shared__ __align__(16) unsigned short Bs[TN * TK];   // 16 KB

    int tid = threadIdx.x;
    int lane = tid & 63, wv = tid >> 6;   // 4 waves
    int wr = (wv >> 1) * 64;              // wave row offset in C-tile
    int wc = (wv & 1) * 64;               // wave col offset in C-tile

    int rowg = lane >> 3;            // 0..7 row within 8-row group
    int sl   = (lane & 7) ^ rowg;    // swizzled source chunk for staging

    const unsigned short* ag[4];
    const unsigned short* bg[4];
#pragma unroll
    for (int i = 0; i < 4; ++i) {
        int r = wv * 32 + i * 8 + rowg;          // A tile row 0..127
        int gr = m0 + r;
        int tokrow = (gr < cnt) ? list[e * N + gr] : 0;
        ag[i] = X + (size_t)tokrow * H + sl * 8;
    }
#pragma unroll
    for (int i = 0; i < 4; ++i) {
        int r = wv * 32 + i * 8 + rowg;          // B tile row 0..127
        int wrow = (r & 1) * Ie + nt * 64 + (r >> 1);
        bg[i] = Wt + ((size_t)e * F2 + wrow) * H + sl * 8;
    }

    f32x4 acc[4][4];
#pragma unroll
    for (int i = 0; i < 4; ++i)
#pragma unroll
        for (int j = 0; j < 4; ++j) acc[i][j] = (f32x4)(0.f);

    int q = lane >> 4, m = lane & 15;
    int sw = m & 7;

    for (int k0 = 0; k0 < H; k0 += TK) {
#pragma unroll
        for (int i = 0; i < 4; ++i)
            ld16(ag[i] + k0, &As[(wv * 32 + i * 8) * TK]);
#pragma unroll
        for (int i = 0; i < 4; ++i)
            ld16(bg[i] + k0, &Bs[(wv * 32 + i * 8) * TK]);
        __syncthreads();
#pragma unroll
        for (int ks = 0; ks < TK; ks += 32) {
            int kc = ks >> 3;
            int ck = ((kc + q) ^ sw) << 3;
            bf16x8 af[4], bfr[4];
#pragma unroll
            for (int im = 0; im < 4; ++im)
                af[im] = *(const bf16x8*)&As[(wr + m + im * 16) * TK + ck];
#pragma unroll
            for (int in_ = 0; in_ < 4; ++in_)
                bfr[in_] = *(const bf16x8*)&Bs[(wc + m + in_ * 16) * TK + ck];
#pragma unroll
            for (int im = 0; im < 4; ++im)
#pragma unroll
                for (int in_ = 0; in_ < 4; ++in_)
                    acc[im][in_] = __builtin_amdgcn_mfma_f32_16x16x32_bf16(
                        af[im], bfr[in_], acc[im][in_], 0, 0, 0);
        }
        __syncthreads();
    }

    // epilogue: pair even(gate)/odd(up) lanes, silu in fp32, write IT
    int b = base_[e];
    int nt64 = nt * 64;
#pragma unroll
    for (int im = 0; im < 4; ++im) {
#pragma unroll
        for (int j = 0; j < 4; ++j) {
            int row = wr + im * 16 + q * 4 + j;
            int gr = m0 + row;
#pragma unroll
            for (int in_ = 0; in_ < 4; ++in_) {
                float v = acc[im][in_][j];
                float u = __shfl_xor(v, 1);
                float g = v;
                float s = g / (1.f + __expf(-g));
                float res = s * u;
                if (!(lane & 1) && gr < cnt) {
                    int oc = nt64 + ((wc + in_ * 16 + m) >> 1);
                    IT[(size_t)(b + gr) * Ie + oc] = f2bf(res);
                }
            }
        }
    }
}

// GEMM2: OUT[token][H] = IT[compact_row][Ie] @ Wd^T, rows scattered by list
__global__ __launch_bounds__(256, 3) void k_gemm_down(
    const unsigned short* __restrict__ IT,   // [N][Ie] bf16 compact
    const unsigned short* __restrict__ Wt,   // [E][H][Ie] bf16 (h-major)
    float* __restrict__ OUT,                 // [N][H] fp32 token-order
    const int* __restrict__ counts, const int* __restrict__ base_,
    const int* __restrict__ list, int N, int Ie, int H) {
    int bid = blockIdx.x;
    int e = bid & 7;                 // XCD-pinned expert
    int t = bid >> 3;
    int nt = t & 7;                  // H/TN = 8
    int mt = t >> 3;
    int cnt = counts[e];
    int m0 = mt * TM;
    if (m0 >= cnt) return;
    int n0 = nt * TN;
    int b = base_[e];

    __shared__ __align__(16) unsigned short As[TM * TK];
    __shared__ __align__(16) unsigned short Bs[TN * TK];

    int tid = threadIdx.x;
    int lane = tid & 63, wv = tid >> 6;
    int wr = (wv >> 1) * 64;
    int wc = (wv & 1) * 64;

    int rowg = lane >> 3;
    int sl   = (lane & 7) ^ rowg;

    const unsigned short* We = Wt + ((size_t)e * H + n0) * Ie;
    const unsigned short* ag[4];
    const unsigned short* bg[4];
#pragma unroll
    for (int i = 0; i < 4; ++i) {
        int r = wv * 32 + i * 8 + rowg;
        int gr = m0 + r;
        int arow = (gr < cnt) ? (b + gr) : b;
        ag[i] = IT + (size_t)arow * Ie + sl * 8;
    }
#pragma unroll
    for (int i = 0; i < 4; ++i) {
        int r = wv * 32 + i * 8 + rowg;
        bg[i] = We + (size_t)r * Ie + sl * 8;
    }

    f32x4 acc[4][4];
#pragma unroll
    for (int i = 0; i < 4; ++i)
#pragma unroll
        for (int j = 0; j < 4; ++j) acc[i][j] = (f32x4)(0.f);

    int q = lane >> 4, m = lane & 15;
    int sw = m & 7;

    for (int k0 = 0; k0 < Ie; k0 += TK) {
#pragma unroll
        for (int i = 0; i < 4; ++i)
            ld16(ag[i] + k0, &As[(wv * 32 + i * 8) * TK]);
#pragma unroll
        for (int i = 0; i < 4; ++i)
            ld16(bg[i] + k0, &Bs[(wv * 32 + i * 8) * TK]);
        __syncthreads();
#pragma unroll
        for (int ks = 0; ks < TK; ks += 32) {
            int kc = ks >> 3;
            int ck = ((kc + q) ^ sw) << 3;
            bf16x8 af[4], bfr[4];
#pragma unroll
            for (int im = 0; im < 4; ++im)
                af[im] = *(const bf16x8*)&As[(wr + m + im * 16) * TK + ck];
#pragma unroll
            for (int in_ = 0; in_ < 4; ++in_)
                bfr[in_] = *(const bf16x8*)&Bs[(wc + m + in_ * 16) * TK + ck];
#pragma unroll
            for (int im = 0; im < 4; ++im)
#pragma unroll
                for (int in_ = 0; in_ < 4; ++in_)
                    acc[im][in_] = __builtin_amdgcn_mfma_f32_16x16x32_bf16(
                        af[im], bfr[in_], acc[im][in_], 0, 0, 0);
        }
        __syncthreads();
    }

#pragma unroll
    for (int im = 0; im < 4; ++im) {
#pragma unroll
        for (int j = 0; j < 4; ++j) {
            int row = wr + im * 16 + q * 4 + j;
            int gr = m0 + row;
            if (gr < cnt) {
                int tok = list[e * N + gr];
                float* orow = OUT + (size_t)tok * H + n0;
#pragma unroll
                for (int in_ = 0; in_ < 4; ++in_) {
                    int col = wc + in_ * 16 + m;
                    orow[col] = acc[im][in_][j];
                }
            }
        }
    }
}

extern "C" void kernel_launch(void* const* d_in, const int* in_sizes, int n_in,
                              void* d_out, int out_size, void* d_ws, size_t ws_size,
                              hipStream_t stream) {
    const float* hidden   = (const float*)d_in[0];
    const int*   tok_ids  = (const int*)d_in[1];
    const float* mu       = (const float*)d_in[2];
    const float* gup      = (const float*)d_in[3];
    const float* dnp      = (const float*)d_in[4];
    const float* rw       = (const float*)d_in[5];
    float* out = (float*)d_out;

    int N  = in_sizes[1];                 // 8192
    int H  = in_sizes[0] / N;             // 1024
    int E  = in_sizes[5] / H;             // 8
    int F2 = in_sizes[3] / (E * H);       // 1024
    int Ie = F2 / 2;                      // 512

    int NB = (N + 255) / 256;             // 32

    char* ws = (char*)d_ws;
    size_t o = 0;
    auto alloc = [&](size_t sz) {
        size_t r = o;
        o += (sz + 255) & ~(size_t)255;
        return r;
    };
    int* counts   = (int*)(ws + alloc((size_t)E * 4));
    int* base_    = (int*)(ws + alloc((size_t)E * 4));
    int* eids     = (int*)(ws + alloc((size_t)N * 4));
    int* blockcnt = (int*)(ws + alloc((size_t)NB * 8 * 4));
    int* offs     = (int*)(ws + alloc((size_t)NB * 8 * 4));
    int* list     = (int*)(ws + alloc((size_t)E * N * 4));
    unsigned short* xb   = (unsigned short*)(ws + alloc((size_t)N * H * 2));
    unsigned short* wgut = (unsigned short*)(ws + alloc((size_t)E * F2 * H * 2));
    unsigned short* wdnt = (unsigned short*)(ws + alloc((size_t)E * H * Ie * 2));
    unsigned short* it   = (unsigned short*)(ws + alloc((size_t)N * Ie * 2));

    k_prep<<<dim3((N + 3) / 4), dim3(256), 0, stream>>>(hidden, mu, tok_ids, rw, xb, eids, H, N);

    k_transpose_all<<<dim3(16, 16, 16), dim3(256), 0, stream>>>(gup, dnp, wgut, wdnt, H, F2, Ie);

    k_count<<<dim3(NB), dim3(256), 0, stream>>>(eids, blockcnt, N);
    k_scan<<<dim3(1), dim3(64), 0, stream>>>(blockcnt, counts, base_, offs, NB);
    k_scatter<<<dim3(NB), dim3(256), 0, stream>>>(eids, offs, list, N);

    int MT = (N + TM - 1) / TM;           // 64
    // flat XCD-pinned grids: bid&7 = expert
    k_gemm_gateup<<<dim3(E * MT * (Ie / 64)), dim3(256), 0, stream>>>(
        xb, wgut, it, counts, base_, list, N, H, Ie);

    k_gemm_down<<<dim3(E * MT * (H / TN)), dim3(256), 0, stream>>>(
        it, wdnt, out, counts, base_, list, N, Ie, H);
}